// Round 9
// baseline (230.639 us; speedup 1.0000x reference)
//
#include <hip/hip_runtime.h>
#include <math.h>

#define BATCH    2
#define SEQ      2048
#define DIM      1024
#define HEADS    16
#define HEAD_DIM 64
#define K_NEI    64
#define QKV_DIM  3072
#define MROWS    (BATCH * SEQ)   // 4096
#define ATT_SCALE 0.125f

typedef _Float16 half8  __attribute__((ext_vector_type(8)));
typedef _Float16 half4  __attribute__((ext_vector_type(4)));
typedef _Float16 half2t __attribute__((ext_vector_type(2)));
typedef float    floatx4  __attribute__((ext_vector_type(4)));
typedef float    floatx16 __attribute__((ext_vector_type(16)));

__device__ inline void async_copy16(const void* g, void* l) {
  __builtin_amdgcn_global_load_lds(
      (const __attribute__((address_space(1))) unsigned int*)g,
      (__attribute__((address_space(3))) unsigned int*)l, 16, 0, 0);
}

__device__ inline float dot2h(half2t a, half2t b, float c) {
#if defined(__has_builtin) && __has_builtin(__builtin_amdgcn_fdot2)
  return __builtin_amdgcn_fdot2(a, b, c, false);
#else
  return c + (float)a[0] * (float)b[0] + (float)a[1] * (float)b[1];
#endif
}

// fused fp32 -> f16 cast of three tensors (sizes in float4 groups)
__global__ __launch_bounds__(256)
void cast3(const float* __restrict__ a, int na4,
           const float* __restrict__ b, int nb4,
           const float* __restrict__ c, int nc4,
           _Float16* __restrict__ oa, _Float16* __restrict__ ob,
           _Float16* __restrict__ oc) {
  const int total = na4 + nb4 + nc4;
  for (int i = blockIdx.x * blockDim.x + threadIdx.x; i < total;
       i += gridDim.x * blockDim.x) {
    const float* src; _Float16* dst; int idx;
    if (i < na4)            { src = a; dst = oa; idx = i; }
    else if (i < na4 + nb4) { src = b; dst = ob; idx = i - na4; }
    else                    { src = c; dst = oc; idx = i - na4 - nb4; }
    float4 v = *(const float4*)(src + (size_t)idx * 4);
    half4 o;
    o[0] = (_Float16)v.x; o[1] = (_Float16)v.y;
    o[2] = (_Float16)v.z; o[3] = (_Float16)v.w;
    *(half4*)(dst + (size_t)idx * 4) = o;
  }
}

// C[m,n] = sum_k A[m,k]*B[n,k] + bias[n]; A:[M,K] f16, B:[N,K] f16.
// 32x32x16 MFMA fragments (m119: +15% per-issue vs 16x16x32, half the MFMA
// instruction count per wave-tile). BK=64 staged as two 32-wide sub-tiles.
// Wave grid 2x2, per-wave tile (BM/2)x(BN/2) as 32x32 frags.
// HALF_OUT: swapped operands -> D'[n][m]; lane&31 = m, regs sweep n -> half4
// stores. C/D layout (m74/m101): col=lane&31, row=(reg&3)+8*(reg>>2)+4*(lane>>5).
template<int BM, int BN, bool HALF_OUT>
__global__ __launch_bounds__(256)
void gemm_bt_f16(const _Float16* __restrict__ A, const _Float16* __restrict__ B,
                 const float* __restrict__ bias, void* __restrict__ Cv,
                 int M, int N, int K) {
  constexpr int FI = BM / 64;   // 32x32 frags per wave (m)
  constexpr int FJ = BN / 64;   // 32x32 frags per wave (n)
  constexpr int CA = BM / 64;   // staging instrs per thread per sub-tile
  constexpr int CB = BN / 64;
  __shared__ _Float16 As[2 * BM * 32];
  __shared__ _Float16 Bs[2 * BN * 32];

  const int tid  = threadIdx.x;
  const int lane = tid & 63;
  const int w    = tid >> 6;
  const int wr   = w >> 1;
  const int wc   = w & 1;
  const int bm   = blockIdx.y * BM;
  const int bn   = blockIdx.x * BN;

  const int srow = w * 16 + (lane >> 2);
  const int scol = (lane & 3) * 8;
  const _Float16* ga = A + (size_t)(bm + srow) * K + scol;
  const _Float16* gb = B + (size_t)(bn + srow) * K + scol;

  // 32x32x16 A/B fragment addressing: row/col = lane&31, k-octet = (lane>>5)*8
  const int frow = lane & 31;
  const int fo   = (lane >> 5) * 8;

  floatx16 acc[FI][FJ] = {};

  for (int k0 = 0; k0 < K; k0 += 64) {
#pragma unroll
    for (int sub = 0; sub < 2; sub++) {
      const int kk = k0 + sub * 32;
#pragma unroll
      for (int i = 0; i < CA; i++)
        async_copy16(ga + (size_t)(i * 64) * K + kk,
                     As + sub * BM * 32 + w * 512 + i * 2048);
#pragma unroll
      for (int i = 0; i < CB; i++)
        async_copy16(gb + (size_t)(i * 64) * K + kk,
                     Bs + sub * BN * 32 + w * 512 + i * 2048);
    }
    __syncthreads();

#pragma unroll
    for (int sub = 0; sub < 2; sub++) {
#pragma unroll
      for (int ks = 0; ks < 2; ks++) {     // two K=16 steps per 32-sub-tile
        half8 af[FI], bf[FJ];
#pragma unroll
        for (int i = 0; i < FI; i++)
          af[i] = *(const half8*)&As[sub * BM * 32 +
                                     (wr * (BM / 2) + i * 32 + frow) * 32 + ks * 16 + fo];
#pragma unroll
        for (int j = 0; j < FJ; j++)
          bf[j] = *(const half8*)&Bs[sub * BN * 32 +
                                     (wc * (BN / 2) + j * 32 + frow) * 32 + ks * 16 + fo];
#pragma unroll
        for (int i = 0; i < FI; i++)
#pragma unroll
          for (int j = 0; j < FJ; j++) {
            if (HALF_OUT)
              acc[i][j] = __builtin_amdgcn_mfma_f32_32x32x16_f16(bf[j], af[i], acc[i][j], 0, 0, 0);
            else
              acc[i][j] = __builtin_amdgcn_mfma_f32_32x32x16_f16(af[i], bf[j], acc[i][j], 0, 0, 0);
          }
      }
    }
    __syncthreads();
  }

  if (HALF_OUT) {
    _Float16* C = (_Float16*)Cv;
#pragma unroll
    for (int i = 0; i < FI; i++) {
      const int m = bm + wr * (BM / 2) + i * 32 + (lane & 31);
#pragma unroll
      for (int j = 0; j < FJ; j++) {
        const int nbase = bn + wc * (BN / 2) + j * 32 + 4 * (lane >> 5);
#pragma unroll
        for (int rq = 0; rq < 4; rq++) {
          const int n = nbase + 8 * rq;
          float4 bj = *(const float4*)(bias + n);
          half4 hv;
          hv[0] = (_Float16)(acc[i][j][4 * rq + 0] + bj.x);
          hv[1] = (_Float16)(acc[i][j][4 * rq + 1] + bj.y);
          hv[2] = (_Float16)(acc[i][j][4 * rq + 2] + bj.z);
          hv[3] = (_Float16)(acc[i][j][4 * rq + 3] + bj.w);
          *(half4*)(C + (size_t)m * N + n) = hv;
        }
      }
    }
  } else {
    float* C = (float*)Cv;
#pragma unroll
    for (int j = 0; j < FJ; j++) {
      const int col = bn + wc * (BN / 2) + j * 32 + (lane & 31);
      const float bj = bias[col];
#pragma unroll
      for (int i = 0; i < FI; i++) {
        const int rbase = bm + wr * (BM / 2) + i * 32 + 4 * (lane >> 5);
#pragma unroll
        for (int rq = 0; rq < 4; rq++)
#pragma unroll
          for (int rr = 0; rr < 4; rr++) {
            const int row = rbase + 8 * rq + rr;
            C[(size_t)row * N + col] = acc[i][j][4 * rq + rr] + bj;
          }
      }
    }
  }
}

// Quad-cooperative gathered attention, LDS-transpose reduction (round-8
// version, measured 80.8 us — frozen; limiter is the gather VMEM stream).
__global__ __launch_bounds__(256)
void attn_kernel(const _Float16* __restrict__ qkv,
                 const int* __restrict__ routes,
                 _Float16* __restrict__ ao) {
  const int lane = threadIdx.x & 63;
  const int w    = threadIdx.x >> 6;
  const int g    = lane >> 4;
  const int c    = lane & 15;

  const int i    = blockIdx.x;
  const int xcd  = i & 7;
  const int j    = i >> 3;
  const int bh   = j >> 6;
  const int qsub = j & 63;
  const int qblk = xcd * 64 + qsub;
  const int q    = qblk * 4 + w;
  const int h    = bh & 15;
  const int b    = bh >> 4;

  __shared__ float scratch[4][16 * 68];
  float* sw = scratch[w];

  const size_t row_base = (size_t)b * SEQ;
  const int    hoff     = h * HEAD_DIM;

  const int* rbase = routes + q * K_NEI + g;
  int rq[16];
#pragma unroll
  for (int t = 0; t < 16; t++) rq[t] = rbase[4 * t];

  const half4 qv = *(const half4*)(qkv + (row_base + q) * QKV_DIM + hoff + 4 * c);
  const half2t qv01 = { qv[0], qv[1] };
  const half2t qv23 = { qv[2], qv[3] };

  half4 vv[16];

#pragma unroll
  for (int t = 0; t < 16; t++) {
    const _Float16* kp = qkv + (row_base + rq[t]) * QKV_DIM + DIM + hoff + 4 * c;
    half4 kv = *(const half4*)kp;
    vv[t]    = *(const half4*)(kp + DIM);
    half2t k01 = { kv[0], kv[1] };
    half2t k23 = { kv[2], kv[3] };
    float sp = dot2h(k23, qv23, dot2h(k01, qv01, 0.f));
    sw[t * 68 + lane] = sp;
  }

  const int rb = (lane >> 2) * 68 + (lane & 3) * 16;
  float4 p0 = *(const float4*)&sw[rb];
  float4 p1 = *(const float4*)&sw[rb + 4];
  float4 p2 = *(const float4*)&sw[rb + 8];
  float4 p3 = *(const float4*)&sw[rb + 12];
  float sc = ((p0.x + p0.y) + (p0.z + p0.w)) + ((p1.x + p1.y) + (p1.z + p1.w))
           + ((p2.x + p2.y) + (p2.z + p2.w)) + ((p3.x + p3.y) + (p3.z + p3.w));

  float m = sc;
#pragma unroll
  for (int off = 1; off < 64; off <<= 1) m = fmaxf(m, __shfl_xor(m, off));
  float e = __expf((sc - m) * ATT_SCALE);
  float sum = e;
#pragma unroll
  for (int off = 1; off < 64; off <<= 1) sum += __shfl_xor(sum, off);
  const float pn = e / sum;

  sw[lane] = pn;
  float o0 = 0.f, o1 = 0.f, o2 = 0.f, o3 = 0.f;
#pragma unroll
  for (int t = 0; t < 16; t++) {
    const float p = sw[4 * t + g];
    o0 += p * (float)vv[t][0];
    o1 += p * (float)vv[t][1];
    o2 += p * (float)vv[t][2];
    o3 += p * (float)vv[t][3];
  }
  o0 += __shfl_xor(o0, 16); o0 += __shfl_xor(o0, 32);
  o1 += __shfl_xor(o1, 16); o1 += __shfl_xor(o1, 32);
  o2 += __shfl_xor(o2, 16); o2 += __shfl_xor(o2, 32);
  o3 += __shfl_xor(o3, 16); o3 += __shfl_xor(o3, 32);

  if (g == 0) {
    half4 hv;
    hv[0] = (_Float16)o0; hv[1] = (_Float16)o1;
    hv[2] = (_Float16)o2; hv[3] = (_Float16)o3;
    *(half4*)(ao + (row_base + q) * DIM + hoff + 4 * c) = hv;
  }
}

extern "C" void kernel_launch(void* const* d_in, const int* in_sizes, int n_in,
                              void* d_out, int out_size, void* d_ws, size_t ws_size,
                              hipStream_t stream) {
  const float* x      = (const float*)d_in[0];
  const int*   routes = (const int*)  d_in[1];
  const float* qkv_w  = (const float*)d_in[2];
  const float* qkv_b  = (const float*)d_in[3];
  const float* out_w  = (const float*)d_in[4];
  const float* out_b  = (const float*)d_in[5];
  float* out = (float*)d_out;

  _Float16* qkvh = (_Float16*)d_ws;                       // 4096*3072
  _Float16* aoh  = qkvh + (size_t)MROWS * QKV_DIM;        // 4096*1024
  _Float16* xh   = aoh  + (size_t)MROWS * DIM;            // 4096*1024
  _Float16* wh   = xh   + (size_t)MROWS * DIM;            // 3072*1024
  _Float16* owh  = wh   + (size_t)QKV_DIM * DIM;          // 1024*1024

  cast3<<<1024, 256, 0, stream>>>(x, MROWS * DIM / 4,
                                  qkv_w, QKV_DIM * DIM / 4,
                                  out_w, DIM * DIM / 4,
                                  xh, wh, owh);

  // QKV projection: 128x128 tile, 768 blocks, 32x32x16 frags
  {
    dim3 g(QKV_DIM / 128, MROWS / 128);
    gemm_bt_f16<128, 128, true><<<g, 256, 0, stream>>>(xh, wh, qkv_b, qkvh,
                                                       MROWS, QKV_DIM, DIM);
  }

  attn_kernel<<<(BATCH * HEADS * SEQ) / 4, 256, 0, stream>>>(qkvh, routes, aoh);

  // output projection: 64x128 tile -> 512 blocks
  {
    dim3 g(DIM / 128, MROWS / 64);
    gemm_bt_f16<64, 128, false><<<g, 256, 0, stream>>>(aoh, owh, out_b, out,
                                                       MROWS, DIM, DIM);
  }
}

// Round 10
// 220.462 us; speedup vs baseline: 1.0462x; 1.0462x over previous
//
#include <hip/hip_runtime.h>
#include <math.h>

#define BATCH    2
#define SEQ      2048
#define DIM      1024
#define HEADS    16
#define HEAD_DIM 64
#define K_NEI    64
#define QKV_DIM  3072
#define MROWS    (BATCH * SEQ)   // 4096
#define ATT_SCALE 0.125f

typedef _Float16 half8  __attribute__((ext_vector_type(8)));
typedef _Float16 half4  __attribute__((ext_vector_type(4)));
typedef _Float16 half2t __attribute__((ext_vector_type(2)));
typedef float    floatx4 __attribute__((ext_vector_type(4)));

__device__ inline void async_copy16(const void* g, void* l) {
  __builtin_amdgcn_global_load_lds(
      (const __attribute__((address_space(1))) unsigned int*)g,
      (__attribute__((address_space(3))) unsigned int*)l, 16, 0, 0);
}

__device__ inline float dot2h(half2t a, half2t b, float c) {
#if defined(__has_builtin) && __has_builtin(__builtin_amdgcn_fdot2)
  return __builtin_amdgcn_fdot2(a, b, c, false);
#else
  return c + (float)a[0] * (float)b[0] + (float)a[1] * (float)b[1];
#endif
}

// fused fp32 -> f16 cast of three tensors (sizes in float4 groups)
__global__ __launch_bounds__(256)
void cast3(const float* __restrict__ a, int na4,
           const float* __restrict__ b, int nb4,
           const float* __restrict__ c, int nc4,
           _Float16* __restrict__ oa, _Float16* __restrict__ ob,
           _Float16* __restrict__ oc) {
  const int total = na4 + nb4 + nc4;
  for (int i = blockIdx.x * blockDim.x + threadIdx.x; i < total;
       i += gridDim.x * blockDim.x) {
    const float* src; _Float16* dst; int idx;
    if (i < na4)            { src = a; dst = oa; idx = i; }
    else if (i < na4 + nb4) { src = b; dst = ob; idx = i - na4; }
    else                    { src = c; dst = oc; idx = i - na4 - nb4; }
    float4 v = *(const float4*)(src + (size_t)idx * 4);
    half4 o;
    o[0] = (_Float16)v.x; o[1] = (_Float16)v.y;
    o[2] = (_Float16)v.z; o[3] = (_Float16)v.w;
    *(half4*)(dst + (size_t)idx * 4) = o;
  }
}

// C[m,n] = sum_k A[m,k]*B[n,k] + bias[n]; A:[M,K] f16, B:[N,K] f16.
// Round-8 measured-best config: 16x16x32 MFMA, BK=64 as two 32-wide sub-tiles.
template<int BM, int BN, bool HALF_OUT>
__global__ __launch_bounds__(256)
void gemm_bt_f16(const _Float16* __restrict__ A, const _Float16* __restrict__ B,
                 const float* __restrict__ bias, void* __restrict__ Cv,
                 int M, int N, int K) {
  constexpr int FI = BM / 32;
  constexpr int FJ = BN / 32;
  constexpr int CA = BM / 64;
  constexpr int CB = BN / 64;
  __shared__ _Float16 As[2 * BM * 32];
  __shared__ _Float16 Bs[2 * BN * 32];

  const int tid  = threadIdx.x;
  const int lane = tid & 63;
  const int w    = tid >> 6;
  const int wr   = w >> 1;
  const int wc   = w & 1;
  const int bm   = blockIdx.y * BM;
  const int bn   = blockIdx.x * BN;

  const int srow = w * 16 + (lane >> 2);
  const int scol = (lane & 3) * 8;
  const _Float16* ga = A + (size_t)(bm + srow) * K + scol;
  const _Float16* gb = B + (size_t)(bn + srow) * K + scol;

  const int frow = lane & 15;
  const int fk   = (lane >> 4) * 8;

  floatx4 acc[FI][FJ] = {};

  for (int k0 = 0; k0 < K; k0 += 64) {
#pragma unroll
    for (int sub = 0; sub < 2; sub++) {
      const int kk = k0 + sub * 32;
#pragma unroll
      for (int i = 0; i < CA; i++)
        async_copy16(ga + (size_t)(i * 64) * K + kk,
                     As + sub * BM * 32 + w * 512 + i * 2048);
#pragma unroll
      for (int i = 0; i < CB; i++)
        async_copy16(gb + (size_t)(i * 64) * K + kk,
                     Bs + sub * BN * 32 + w * 512 + i * 2048);
    }
    __syncthreads();

#pragma unroll
    for (int sub = 0; sub < 2; sub++) {
      half8 af[FI], bf[FJ];
#pragma unroll
      for (int i = 0; i < FI; i++)
        af[i] = *(const half8*)&As[sub * BM * 32 + (wr * (BM / 2) + i * 16 + frow) * 32 + fk];
#pragma unroll
      for (int j = 0; j < FJ; j++)
        bf[j] = *(const half8*)&Bs[sub * BN * 32 + (wc * (BN / 2) + j * 16 + frow) * 32 + fk];
#pragma unroll
      for (int i = 0; i < FI; i++)
#pragma unroll
        for (int j = 0; j < FJ; j++) {
          if (HALF_OUT)
            acc[i][j] = __builtin_amdgcn_mfma_f32_16x16x32_f16(bf[j], af[i], acc[i][j], 0, 0, 0);
          else
            acc[i][j] = __builtin_amdgcn_mfma_f32_16x16x32_f16(af[i], bf[j], acc[i][j], 0, 0, 0);
        }
    }
    __syncthreads();
  }

  if (HALF_OUT) {
    _Float16* C = (_Float16*)Cv;
    const int mloc = lane & 15;
    const int nloc = (lane >> 4) * 4;
#pragma unroll
    for (int j = 0; j < FJ; j++) {
      const int gcol = bn + wc * (BN / 2) + j * 16 + nloc;
      float4 bj = *(const float4*)(bias + gcol);
#pragma unroll
      for (int i = 0; i < FI; i++) {
        const int grow = bm + wr * (BM / 2) + i * 16 + mloc;
        half4 hv;
        hv[0] = (_Float16)(acc[i][j][0] + bj.x);
        hv[1] = (_Float16)(acc[i][j][1] + bj.y);
        hv[2] = (_Float16)(acc[i][j][2] + bj.z);
        hv[3] = (_Float16)(acc[i][j][3] + bj.w);
        *(half4*)(C + (size_t)grow * N + gcol) = hv;
      }
    }
  } else {
    float* C = (float*)Cv;
    const int crow = (lane >> 4) * 4;
    const int ccol = lane & 15;
#pragma unroll
    for (int j = 0; j < FJ; j++) {
      const int gcol = bn + wc * (BN / 2) + j * 16 + ccol;
      const float bj = bias[gcol];
#pragma unroll
      for (int i = 0; i < FI; i++) {
        const int grow = bm + wr * (BM / 2) + i * 16 + crow;
        float* cp = C + (size_t)grow * N + gcol;
#pragma unroll
        for (int r = 0; r < 4; r++)
          cp[(size_t)r * N] = acc[i][j][r] + bj;
      }
    }
  }
}

// Head-amortized gathered attention: one block per (b,q); wave w = heads
// 4w..4w+3; lane = (head hh = lane>>4, dims 4*(lane&15)). Routes are
// q-only, so all heads share the gather: each K/V load instruction reads one
// row's 512B contiguous span (offset 256w + 4*lane -> zero divergence),
// row scalar via readlane -> SGPR base. Scores: r8 LDS-transpose per
// 16-route chunk; softmax over lane-bits 0..3 per head; unnormalized e to
// LDS (stride-68 per head); V loop: 16 broadcast b128 p-reads + fma_mix;
// normalize at end. Wave-private LDS, zero barriers.
__global__ __launch_bounds__(256)
void attn_kernel(const _Float16* __restrict__ qkv,
                 const int* __restrict__ routes,
                 _Float16* __restrict__ ao) {
  const int lane = threadIdx.x & 63;
  const int w    = threadIdx.x >> 6;

  // XCD swizzle: contiguous 256-q band per XCD (route locality in L2)
  const int i    = blockIdx.x;          // 0..4095
  const int xcd  = i & 7;
  const int j    = i >> 3;              // 0..511
  const int b    = j >> 8;
  const int q    = xcd * 256 + (j & 255);

  __shared__ float scratch[4][16 * 68];
  float* sw = scratch[w];

  const size_t row_base = (size_t)b * SEQ;
  const int    rowoff   = 256 * w + 4 * lane;   // head (4w+hh), dims 4*(lane&15)

  const int rt = routes[q * K_NEI + lane];      // lane r holds route[r]

  const half4 qv = *(const half4*)(qkv + (row_base + q) * QKV_DIM + rowoff);
  const half2t qv01 = { qv[0], qv[1] };
  const half2t qv23 = { qv[2], qv[3] };

  // ---- scores: 4 chunks of 16 routes; contiguous 512B K loads ----
  float s[4];
#pragma unroll
  for (int cc = 0; cc < 4; cc++) {
#pragma unroll
    for (int t = 0; t < 16; t++) {
      const int ri = __builtin_amdgcn_readlane(rt, 16 * cc + t);
      const half4 kv = *(const half4*)(qkv + (row_base + ri) * QKV_DIM + DIM + rowoff);
      half2t k01 = { kv[0], kv[1] };
      half2t k23 = { kv[2], kv[3] };
      sw[t * 68 + lane] = dot2h(k23, qv23, dot2h(k01, qv01, 0.f));
    }
    // transpose: lane l sums 16 dim-partials of (head l>>4, route 16cc+(l&15))
    const int rb = (lane & 15) * 68 + (lane >> 4) * 16;
    float4 p0 = *(const float4*)&sw[rb];
    float4 p1 = *(const float4*)&sw[rb + 4];
    float4 p2 = *(const float4*)&sw[rb + 8];
    float4 p3 = *(const float4*)&sw[rb + 12];
    s[cc] = ((p0.x + p0.y) + (p0.z + p0.w)) + ((p1.x + p1.y) + (p1.z + p1.w))
          + ((p2.x + p2.y) + (p2.z + p2.w)) + ((p3.x + p3.y) + (p3.z + p3.w));
  }

  // ---- per-head softmax (reduce over lane-bits 0..3) ----
  float m = fmaxf(fmaxf(s[0], s[1]), fmaxf(s[2], s[3]));
#pragma unroll
  for (int off = 1; off < 16; off <<= 1) m = fmaxf(m, __shfl_xor(m, off));
  float e[4];
  float sum = 0.f;
#pragma unroll
  for (int cc = 0; cc < 4; cc++) {
    e[cc] = __expf((s[cc] - m) * ATT_SCALE);
    sum += e[cc];
  }
#pragma unroll
  for (int off = 1; off < 16; off <<= 1) sum += __shfl_xor(sum, off);
  const float rinv = 1.f / sum;

  // unnormalized e -> LDS, route-major per head (stride 68 kills bank alias)
  const int pbase = (lane >> 4) * 68;
#pragma unroll
  for (int cc = 0; cc < 4; cc++)
    sw[pbase + cc * 16 + (lane & 15)] = e[cc];

  // ---- V accumulation: p via broadcast b128, contiguous 512B V loads ----
  float o0 = 0.f, o1 = 0.f, o2 = 0.f, o3 = 0.f;
#pragma unroll
  for (int t = 0; t < 16; t++) {
    const float4 pv = *(const float4*)&sw[pbase + 4 * t];
#pragma unroll
    for (int jj = 0; jj < 4; jj++) {
      const int ri = __builtin_amdgcn_readlane(rt, 4 * t + jj);
      const half4 vv = *(const half4*)(qkv + (row_base + ri) * QKV_DIM + 2 * DIM + rowoff);
      const float p = (jj == 0) ? pv.x : (jj == 1) ? pv.y : (jj == 2) ? pv.z : pv.w;
      o0 += p * (float)vv[0];
      o1 += p * (float)vv[1];
      o2 += p * (float)vv[2];
      o3 += p * (float)vv[3];
    }
  }

  half4 hv;
  hv[0] = (_Float16)(o0 * rinv); hv[1] = (_Float16)(o1 * rinv);
  hv[2] = (_Float16)(o2 * rinv); hv[3] = (_Float16)(o3 * rinv);
  *(half4*)(ao + (row_base + q) * DIM + rowoff) = hv;
}

extern "C" void kernel_launch(void* const* d_in, const int* in_sizes, int n_in,
                              void* d_out, int out_size, void* d_ws, size_t ws_size,
                              hipStream_t stream) {
  const float* x      = (const float*)d_in[0];
  const int*   routes = (const int*)  d_in[1];
  const float* qkv_w  = (const float*)d_in[2];
  const float* qkv_b  = (const float*)d_in[3];
  const float* out_w  = (const float*)d_in[4];
  const float* out_b  = (const float*)d_in[5];
  float* out = (float*)d_out;

  _Float16* qkvh = (_Float16*)d_ws;                       // 4096*3072
  _Float16* aoh  = qkvh + (size_t)MROWS * QKV_DIM;        // 4096*1024
  _Float16* xh   = aoh  + (size_t)MROWS * DIM;            // 4096*1024
  _Float16* wh   = xh   + (size_t)MROWS * DIM;            // 3072*1024
  _Float16* owh  = wh   + (size_t)QKV_DIM * DIM;          // 1024*1024

  cast3<<<1024, 256, 0, stream>>>(x, MROWS * DIM / 4,
                                  qkv_w, QKV_DIM * DIM / 4,
                                  out_w, DIM * DIM / 4,
                                  xh, wh, owh);

  // QKV projection: 128x128 tile, 768 blocks (round-8 config)
  {
    dim3 g(QKV_DIM / 128, MROWS / 128);
    gemm_bt_f16<128, 128, true><<<g, 256, 0, stream>>>(xh, wh, qkv_b, qkvh,
                                                       MROWS, QKV_DIM, DIM);
  }

  // head-amortized attention: one block per (b,q)
  attn_kernel<<<BATCH * SEQ, 256, 0, stream>>>(qkvh, routes, aoh);

  // output projection: 64x128 tile -> 512 blocks (round-8 config)
  {
    dim3 g(DIM / 128, MROWS / 64);
    gemm_bt_f16<64, 128, false><<<g, 256, 0, stream>>>(aoh, owh, out_b, out,
                                                       MROWS, DIM, DIM);
  }
}

// Round 11
// 215.585 us; speedup vs baseline: 1.0698x; 1.0226x over previous
//
#include <hip/hip_runtime.h>
#include <math.h>

#define BATCH    2
#define SEQ      2048
#define DIM      1024
#define HEADS    16
#define HEAD_DIM 64
#define K_NEI    64
#define QKV_DIM  3072
#define MROWS    (BATCH * SEQ)   // 4096
#define ATT_SCALE 0.125f

typedef _Float16 half8  __attribute__((ext_vector_type(8)));
typedef _Float16 half4  __attribute__((ext_vector_type(4)));
typedef _Float16 half2t __attribute__((ext_vector_type(2)));
typedef float    floatx4 __attribute__((ext_vector_type(4)));

__device__ inline void async_copy16(const void* g, void* l) {
  __builtin_amdgcn_global_load_lds(
      (const __attribute__((address_space(1))) unsigned int*)g,
      (__attribute__((address_space(3))) unsigned int*)l, 16, 0, 0);
}

__device__ inline float dot2h(half2t a, half2t b, float c) {
#if defined(__has_builtin) && __has_builtin(__builtin_amdgcn_fdot2)
  return __builtin_amdgcn_fdot2(a, b, c, false);
#else
  return c + (float)a[0] * (float)b[0] + (float)a[1] * (float)b[1];
#endif
}

// fused fp32 -> f16 cast of three tensors (sizes in float4 groups)
__global__ __launch_bounds__(256)
void cast3(const float* __restrict__ a, int na4,
           const float* __restrict__ b, int nb4,
           const float* __restrict__ c, int nc4,
           _Float16* __restrict__ oa, _Float16* __restrict__ ob,
           _Float16* __restrict__ oc) {
  const int total = na4 + nb4 + nc4;
  for (int i = blockIdx.x * blockDim.x + threadIdx.x; i < total;
       i += gridDim.x * blockDim.x) {
    const float* src; _Float16* dst; int idx;
    if (i < na4)            { src = a; dst = oa; idx = i; }
    else if (i < na4 + nb4) { src = b; dst = ob; idx = i - na4; }
    else                    { src = c; dst = oc; idx = i - na4 - nb4; }
    float4 v = *(const float4*)(src + (size_t)idx * 4);
    half4 o;
    o[0] = (_Float16)v.x; o[1] = (_Float16)v.y;
    o[2] = (_Float16)v.z; o[3] = (_Float16)v.w;
    *(half4*)(dst + (size_t)idx * 4) = o;
  }
}

// C[m,n] = sum_k A[m,k]*B[n,k] + bias[n]; A:[M,K] f16, B:[N,K] f16.
// Round-8 measured-best internals: 16x16x32 MFMA, BK=64 as two sub-tiles.
// 1D grid; caller passes NT (n-tiles) and an XCD panel width PN (n-tiles per
// XCD) or PM (m-tiles per XCD): blocks on one XCD share a contiguous panel
// so its 4MB L2 keeps that panel's B (or A) hot instead of thrashing.
template<int BM, int BN, bool HALF_OUT, bool PANEL_BY_N>
__global__ __launch_bounds__(256)
void gemm_bt_f16(const _Float16* __restrict__ A, const _Float16* __restrict__ B,
                 const float* __restrict__ bias, void* __restrict__ Cv,
                 int M, int N, int K, int NT, int PW) {
  // ---- XCD panel swizzle (round-robin block->XCD assumed) ----
  const int id  = blockIdx.x;
  const int xcd = id & 7;
  const int idx = id >> 3;            // index within this XCD's share
  int mt, nt;
  if (PANEL_BY_N) {                    // XCD owns n-tiles [xcd*PW, xcd*PW+PW)
    nt = xcd * PW + (idx % PW);
    mt = idx / PW;
  } else {                             // XCD owns m-tiles
    const int mrows = PW;              // m-tiles per XCD
    mt = xcd * mrows + (idx / NT);
    nt = idx % NT;
  }
  const int bm = mt * BM;
  const int bn = nt * BN;

  constexpr int FI = BM / 32;
  constexpr int FJ = BN / 32;
  constexpr int CA = BM / 64;
  constexpr int CB = BN / 64;
  __shared__ _Float16 As[2 * BM * 32];
  __shared__ _Float16 Bs[2 * BN * 32];

  const int tid  = threadIdx.x;
  const int lane = tid & 63;
  const int w    = tid >> 6;
  const int wr   = w >> 1;
  const int wc   = w & 1;

  const int srow = w * 16 + (lane >> 2);
  const int scol = (lane & 3) * 8;
  const _Float16* ga = A + (size_t)(bm + srow) * K + scol;
  const _Float16* gb = B + (size_t)(bn + srow) * K + scol;

  const int frow = lane & 15;
  const int fk   = (lane >> 4) * 8;

  floatx4 acc[FI][FJ] = {};

  for (int k0 = 0; k0 < K; k0 += 64) {
#pragma unroll
    for (int sub = 0; sub < 2; sub++) {
      const int kk = k0 + sub * 32;
#pragma unroll
      for (int i = 0; i < CA; i++)
        async_copy16(ga + (size_t)(i * 64) * K + kk,
                     As + sub * BM * 32 + w * 512 + i * 2048);
#pragma unroll
      for (int i = 0; i < CB; i++)
        async_copy16(gb + (size_t)(i * 64) * K + kk,
                     Bs + sub * BN * 32 + w * 512 + i * 2048);
    }
    __syncthreads();

#pragma unroll
    for (int sub = 0; sub < 2; sub++) {
      half8 af[FI], bf[FJ];
#pragma unroll
      for (int i = 0; i < FI; i++)
        af[i] = *(const half8*)&As[sub * BM * 32 + (wr * (BM / 2) + i * 16 + frow) * 32 + fk];
#pragma unroll
      for (int j = 0; j < FJ; j++)
        bf[j] = *(const half8*)&Bs[sub * BN * 32 + (wc * (BN / 2) + j * 16 + frow) * 32 + fk];
#pragma unroll
      for (int i = 0; i < FI; i++)
#pragma unroll
        for (int j = 0; j < FJ; j++) {
          if (HALF_OUT)
            acc[i][j] = __builtin_amdgcn_mfma_f32_16x16x32_f16(bf[j], af[i], acc[i][j], 0, 0, 0);
          else
            acc[i][j] = __builtin_amdgcn_mfma_f32_16x16x32_f16(af[i], bf[j], acc[i][j], 0, 0, 0);
        }
    }
    __syncthreads();
  }

  if (HALF_OUT) {
    _Float16* C = (_Float16*)Cv;
    const int mloc = lane & 15;
    const int nloc = (lane >> 4) * 4;
#pragma unroll
    for (int j = 0; j < FJ; j++) {
      const int gcol = bn + wc * (BN / 2) + j * 16 + nloc;
      float4 bj = *(const float4*)(bias + gcol);
#pragma unroll
      for (int i = 0; i < FI; i++) {
        const int grow = bm + wr * (BM / 2) + i * 16 + mloc;
        half4 hv;
        hv[0] = (_Float16)(acc[i][j][0] + bj.x);
        hv[1] = (_Float16)(acc[i][j][1] + bj.y);
        hv[2] = (_Float16)(acc[i][j][2] + bj.z);
        hv[3] = (_Float16)(acc[i][j][3] + bj.w);
        *(half4*)(C + (size_t)grow * N + gcol) = hv;
      }
    }
  } else {
    float* C = (float*)Cv;
    const int crow = (lane >> 4) * 4;
    const int ccol = lane & 15;
#pragma unroll
    for (int j = 0; j < FJ; j++) {
      const int gcol = bn + wc * (BN / 2) + j * 16 + ccol;
      const float bj = bias[gcol];
#pragma unroll
      for (int i = 0; i < FI; i++) {
        const int grow = bm + wr * (BM / 2) + i * 16 + crow;
        float* cp = C + (size_t)grow * N + gcol;
#pragma unroll
        for (int r = 0; r < 4; r++)
          cp[(size_t)r * N] = acc[i][j][r] + bj;
      }
    }
  }
}

// Quad-cooperative gathered attention, LDS-transpose reduction (round-8
// version, measured 80.8 us — frozen: three decompositions all plateau at
// ~80 us; limiter is L2->CU delivery of the 1.07 GB gather).
__global__ __launch_bounds__(256)
void attn_kernel(const _Float16* __restrict__ qkv,
                 const int* __restrict__ routes,
                 _Float16* __restrict__ ao) {
  const int lane = threadIdx.x & 63;
  const int w    = threadIdx.x >> 6;
  const int g    = lane >> 4;
  const int c    = lane & 15;

  const int i    = blockIdx.x;
  const int xcd  = i & 7;
  const int j    = i >> 3;
  const int bh   = j >> 6;
  const int qsub = j & 63;
  const int qblk = xcd * 64 + qsub;
  const int q    = qblk * 4 + w;
  const int h    = bh & 15;
  const int b    = bh >> 4;

  __shared__ float scratch[4][16 * 68];
  float* sw = scratch[w];

  const size_t row_base = (size_t)b * SEQ;
  const int    hoff     = h * HEAD_DIM;

  const int* rbase = routes + q * K_NEI + g;
  int rq[16];
#pragma unroll
  for (int t = 0; t < 16; t++) rq[t] = rbase[4 * t];

  const half4 qv = *(const half4*)(qkv + (row_base + q) * QKV_DIM + hoff + 4 * c);
  const half2t qv01 = { qv[0], qv[1] };
  const half2t qv23 = { qv[2], qv[3] };

  half4 vv[16];

#pragma unroll
  for (int t = 0; t < 16; t++) {
    const _Float16* kp = qkv + (row_base + rq[t]) * QKV_DIM + DIM + hoff + 4 * c;
    half4 kv = *(const half4*)kp;
    vv[t]    = *(const half4*)(kp + DIM);
    half2t k01 = { kv[0], kv[1] };
    half2t k23 = { kv[2], kv[3] };
    float sp = dot2h(k23, qv23, dot2h(k01, qv01, 0.f));
    sw[t * 68 + lane] = sp;
  }

  const int rb = (lane >> 2) * 68 + (lane & 3) * 16;
  float4 p0 = *(const float4*)&sw[rb];
  float4 p1 = *(const float4*)&sw[rb + 4];
  float4 p2 = *(const float4*)&sw[rb + 8];
  float4 p3 = *(const float4*)&sw[rb + 12];
  float sc = ((p0.x + p0.y) + (p0.z + p0.w)) + ((p1.x + p1.y) + (p1.z + p1.w))
           + ((p2.x + p2.y) + (p2.z + p2.w)) + ((p3.x + p3.y) + (p3.z + p3.w));

  float m = sc;
#pragma unroll
  for (int off = 1; off < 64; off <<= 1) m = fmaxf(m, __shfl_xor(m, off));
  float e = __expf((sc - m) * ATT_SCALE);
  float sum = e;
#pragma unroll
  for (int off = 1; off < 64; off <<= 1) sum += __shfl_xor(sum, off);
  const float pn = e / sum;

  sw[lane] = pn;
  float o0 = 0.f, o1 = 0.f, o2 = 0.f, o3 = 0.f;
#pragma unroll
  for (int t = 0; t < 16; t++) {
    const float p = sw[4 * t + g];
    o0 += p * (float)vv[t][0];
    o1 += p * (float)vv[t][1];
    o2 += p * (float)vv[t][2];
    o3 += p * (float)vv[t][3];
  }
  o0 += __shfl_xor(o0, 16); o0 += __shfl_xor(o0, 32);
  o1 += __shfl_xor(o1, 16); o1 += __shfl_xor(o1, 32);
  o2 += __shfl_xor(o2, 16); o2 += __shfl_xor(o2, 32);
  o3 += __shfl_xor(o3, 16); o3 += __shfl_xor(o3, 32);

  if (g == 0) {
    half4 hv;
    hv[0] = (_Float16)o0; hv[1] = (_Float16)o1;
    hv[2] = (_Float16)o2; hv[3] = (_Float16)o3;
    *(half4*)(ao + (row_base + q) * DIM + hoff + 4 * c) = hv;
  }
}

extern "C" void kernel_launch(void* const* d_in, const int* in_sizes, int n_in,
                              void* d_out, int out_size, void* d_ws, size_t ws_size,
                              hipStream_t stream) {
  const float* x      = (const float*)d_in[0];
  const int*   routes = (const int*)  d_in[1];
  const float* qkv_w  = (const float*)d_in[2];
  const float* qkv_b  = (const float*)d_in[3];
  const float* out_w  = (const float*)d_in[4];
  const float* out_b  = (const float*)d_in[5];
  float* out = (float*)d_out;

  _Float16* qkvh = (_Float16*)d_ws;                       // 4096*3072
  _Float16* aoh  = qkvh + (size_t)MROWS * QKV_DIM;        // 4096*1024
  _Float16* xh   = aoh  + (size_t)MROWS * DIM;            // 4096*1024
  _Float16* wh   = xh   + (size_t)MROWS * DIM;            // 3072*1024
  _Float16* owh  = wh   + (size_t)QKV_DIM * DIM;          // 1024*1024

  cast3<<<1024, 256, 0, stream>>>(x, MROWS * DIM / 4,
                                  qkv_w, QKV_DIM * DIM / 4,
                                  out_w, DIM * DIM / 4,
                                  xh, wh, owh);

  // QKV projection: 128x128, 768 blocks; panel-by-n: each XCD owns 3 n-tiles
  // (B panel 768 KB hot in its 4MB L2; B total 6MB would thrash otherwise).
  gemm_bt_f16<128, 128, true, true><<<768, 256, 0, stream>>>(
      xh, wh, qkv_b, qkvh, MROWS, QKV_DIM, DIM,
      QKV_DIM / 128, (QKV_DIM / 128) / 8);

  attn_kernel<<<(BATCH * HEADS * SEQ) / 4, 256, 0, stream>>>(qkvh, routes, aoh);

  // output projection: 64x128, 512 blocks; panel-by-m: each XCD owns 8 m-tiles,
  // B (2MB) stays fully hot per XCD.
  gemm_bt_f16<64, 128, false, false><<<512, 256, 0, stream>>>(
      aoh, owh, out_b, out, MROWS, DIM, DIM,
      DIM / 128, (MROWS / 64) / 8);
}

// Round 12
// 214.801 us; speedup vs baseline: 1.0737x; 1.0037x over previous
//
#include <hip/hip_runtime.h>
#include <math.h>

#define BATCH    2
#define SEQ      2048
#define DIM      1024
#define HEADS    16
#define HEAD_DIM 64
#define K_NEI    64
#define QKV_DIM  3072
#define MROWS    (BATCH * SEQ)   // 4096
#define ATT_SCALE 0.125f

typedef _Float16 half8  __attribute__((ext_vector_type(8)));
typedef _Float16 half4  __attribute__((ext_vector_type(4)));
typedef _Float16 half2t __attribute__((ext_vector_type(2)));
typedef float    floatx4 __attribute__((ext_vector_type(4)));

__device__ inline void async_copy16(const void* g, void* l) {
  __builtin_amdgcn_global_load_lds(
      (const __attribute__((address_space(1))) unsigned int*)g,
      (__attribute__((address_space(3))) unsigned int*)l, 16, 0, 0);
}

__device__ inline float dot2h(half2t a, half2t b, float c) {
#if defined(__has_builtin) && __has_builtin(__builtin_amdgcn_fdot2)
  return __builtin_amdgcn_fdot2(a, b, c, false);
#else
  return c + (float)a[0] * (float)b[0] + (float)a[1] * (float)b[1];
#endif
}

// fused fp32 -> f16 cast of three tensors (sizes in float4 groups)
__global__ __launch_bounds__(256)
void cast3(const float* __restrict__ a, int na4,
           const float* __restrict__ b, int nb4,
           const float* __restrict__ c, int nc4,
           _Float16* __restrict__ oa, _Float16* __restrict__ ob,
           _Float16* __restrict__ oc) {
  const int total = na4 + nb4 + nc4;
  for (int i = blockIdx.x * blockDim.x + threadIdx.x; i < total;
       i += gridDim.x * blockDim.x) {
    const float* src; _Float16* dst; int idx;
    if (i < na4)            { src = a; dst = oa; idx = i; }
    else if (i < na4 + nb4) { src = b; dst = ob; idx = i - na4; }
    else                    { src = c; dst = oc; idx = i - na4 - nb4; }
    float4 v = *(const float4*)(src + (size_t)idx * 4);
    half4 o;
    o[0] = (_Float16)v.x; o[1] = (_Float16)v.y;
    o[2] = (_Float16)v.z; o[3] = (_Float16)v.w;
    *(half4*)(dst + (size_t)idx * 4) = o;
  }
}

// C[m,n] = sum_k A[m,k]*B[n,k] + bias[n]; A:[M,K] f16, B:[N,K] f16.
// Single-barrier ping-pong K-loop (BK=32/stage, double-buffered LDS):
//   {sync; stage(next -> buf^1); compute(cur)}
// Loads for tile k+1 are in flight during tile k's MFMAs instead of being
// drained by a barrier right after issue (the r8 structure's per-iter stall;
// matters at K=1024 where only 16-32 iterations amortize nothing).
template<int BM, int BN, bool HALF_OUT>
__global__ __launch_bounds__(256)
void gemm_bt_f16(const _Float16* __restrict__ A, const _Float16* __restrict__ B,
                 const float* __restrict__ bias, void* __restrict__ Cv,
                 int M, int N, int K) {
  constexpr int FI = BM / 32;
  constexpr int FJ = BN / 32;
  constexpr int CA = BM / 64;   // staging instrs per thread per 32-K tile
  constexpr int CB = BN / 64;
  __shared__ _Float16 As[2][BM * 32];
  __shared__ _Float16 Bs[2][BN * 32];

  const int tid  = threadIdx.x;
  const int lane = tid & 63;
  const int w    = tid >> 6;
  const int wr   = w >> 1;
  const int wc   = w & 1;
  const int bm   = blockIdx.y * BM;
  const int bn   = blockIdx.x * BN;

  const int srow = w * 16 + (lane >> 2);
  const int scol = (lane & 3) * 8;
  const _Float16* ga = A + (size_t)(bm + srow) * K + scol;
  const _Float16* gb = B + (size_t)(bn + srow) * K + scol;

  const int frow = lane & 15;
  const int fk   = (lane >> 4) * 8;

  floatx4 acc[FI][FJ] = {};

  // prologue: stage tile 0 into buf 0
#pragma unroll
  for (int i = 0; i < CA; i++)
    async_copy16(ga + (size_t)(i * 64) * K, &As[0][w * 512 + i * 2048]);
#pragma unroll
  for (int i = 0; i < CB; i++)
    async_copy16(gb + (size_t)(i * 64) * K, &Bs[0][w * 512 + i * 2048]);

  const int nk = K / 32;
  for (int ki = 0; ki < nk; ki++) {
    const int cur = ki & 1;
    __syncthreads();   // tile ki's loads complete; buf cur^1 free to overwrite

    if (ki + 1 < nk) {
      const int kk = (ki + 1) * 32;
#pragma unroll
      for (int i = 0; i < CA; i++)
        async_copy16(ga + (size_t)(i * 64) * K + kk, &As[cur ^ 1][w * 512 + i * 2048]);
#pragma unroll
      for (int i = 0; i < CB; i++)
        async_copy16(gb + (size_t)(i * 64) * K + kk, &Bs[cur ^ 1][w * 512 + i * 2048]);
    }

    half8 af[FI], bf[FJ];
#pragma unroll
    for (int i = 0; i < FI; i++)
      af[i] = *(const half8*)&As[cur][(wr * (BM / 2) + i * 16 + frow) * 32 + fk];
#pragma unroll
    for (int j = 0; j < FJ; j++)
      bf[j] = *(const half8*)&Bs[cur][(wc * (BN / 2) + j * 16 + frow) * 32 + fk];
#pragma unroll
    for (int i = 0; i < FI; i++)
#pragma unroll
      for (int j = 0; j < FJ; j++) {
        if (HALF_OUT)
          acc[i][j] = __builtin_amdgcn_mfma_f32_16x16x32_f16(bf[j], af[i], acc[i][j], 0, 0, 0);
        else
          acc[i][j] = __builtin_amdgcn_mfma_f32_16x16x32_f16(af[i], bf[j], acc[i][j], 0, 0, 0);
      }
  }

  if (HALF_OUT) {
    _Float16* C = (_Float16*)Cv;
    const int mloc = lane & 15;
    const int nloc = (lane >> 4) * 4;
#pragma unroll
    for (int j = 0; j < FJ; j++) {
      const int gcol = bn + wc * (BN / 2) + j * 16 + nloc;
      float4 bj = *(const float4*)(bias + gcol);
#pragma unroll
      for (int i = 0; i < FI; i++) {
        const int grow = bm + wr * (BM / 2) + i * 16 + mloc;
        half4 hv;
        hv[0] = (_Float16)(acc[i][j][0] + bj.x);
        hv[1] = (_Float16)(acc[i][j][1] + bj.y);
        hv[2] = (_Float16)(acc[i][j][2] + bj.z);
        hv[3] = (_Float16)(acc[i][j][3] + bj.w);
        *(half4*)(C + (size_t)grow * N + gcol) = hv;
      }
    }
  } else {
    float* C = (float*)Cv;
    const int crow = (lane >> 4) * 4;
    const int ccol = lane & 15;
#pragma unroll
    for (int j = 0; j < FJ; j++) {
      const int gcol = bn + wc * (BN / 2) + j * 16 + ccol;
      const float bj = bias[gcol];
#pragma unroll
      for (int i = 0; i < FI; i++) {
        const int grow = bm + wr * (BM / 2) + i * 16 + crow;
        float* cp = C + (size_t)grow * N + gcol;
#pragma unroll
        for (int r = 0; r < 4; r++)
          cp[(size_t)r * N] = acc[i][j][r] + bj;
      }
    }
  }
}

// Quad-cooperative gathered attention, LDS-transpose reduction (round-8
// version, measured 80.8 us — frozen: three decompositions all plateau at
// ~80 us; limiter is L2->CU delivery of the 1.07 GB gather).
__global__ __launch_bounds__(256)
void attn_kernel(const _Float16* __restrict__ qkv,
                 const int* __restrict__ routes,
                 _Float16* __restrict__ ao) {
  const int lane = threadIdx.x & 63;
  const int w    = threadIdx.x >> 6;
  const int g    = lane >> 4;
  const int c    = lane & 15;

  const int i    = blockIdx.x;
  const int xcd  = i & 7;
  const int j    = i >> 3;
  const int bh   = j >> 6;
  const int qsub = j & 63;
  const int qblk = xcd * 64 + qsub;
  const int q    = qblk * 4 + w;
  const int h    = bh & 15;
  const int b    = bh >> 4;

  __shared__ float scratch[4][16 * 68];
  float* sw = scratch[w];

  const size_t row_base = (size_t)b * SEQ;
  const int    hoff     = h * HEAD_DIM;

  const int* rbase = routes + q * K_NEI + g;
  int rq[16];
#pragma unroll
  for (int t = 0; t < 16; t++) rq[t] = rbase[4 * t];

  const half4 qv = *(const half4*)(qkv + (row_base + q) * QKV_DIM + hoff + 4 * c);
  const half2t qv01 = { qv[0], qv[1] };
  const half2t qv23 = { qv[2], qv[3] };

  half4 vv[16];

#pragma unroll
  for (int t = 0; t < 16; t++) {
    const _Float16* kp = qkv + (row_base + rq[t]) * QKV_DIM + DIM + hoff + 4 * c;
    half4 kv = *(const half4*)kp;
    vv[t]    = *(const half4*)(kp + DIM);
    half2t k01 = { kv[0], kv[1] };
    half2t k23 = { kv[2], kv[3] };
    float sp = dot2h(k23, qv23, dot2h(k01, qv01, 0.f));
    sw[t * 68 + lane] = sp;
  }

  const int rb = (lane >> 2) * 68 + (lane & 3) * 16;
  float4 p0 = *(const float4*)&sw[rb];
  float4 p1 = *(const float4*)&sw[rb + 4];
  float4 p2 = *(const float4*)&sw[rb + 8];
  float4 p3 = *(const float4*)&sw[rb + 12];
  float sc = ((p0.x + p0.y) + (p0.z + p0.w)) + ((p1.x + p1.y) + (p1.z + p1.w))
           + ((p2.x + p2.y) + (p2.z + p2.w)) + ((p3.x + p3.y) + (p3.z + p3.w));

  float m = sc;
#pragma unroll
  for (int off = 1; off < 64; off <<= 1) m = fmaxf(m, __shfl_xor(m, off));
  float e = __expf((sc - m) * ATT_SCALE);
  float sum = e;
#pragma unroll
  for (int off = 1; off < 64; off <<= 1) sum += __shfl_xor(sum, off);
  const float pn = e / sum;

  sw[lane] = pn;
  float o0 = 0.f, o1 = 0.f, o2 = 0.f, o3 = 0.f;
#pragma unroll
  for (int t = 0; t < 16; t++) {
    const float p = sw[4 * t + g];
    o0 += p * (float)vv[t][0];
    o1 += p * (float)vv[t][1];
    o2 += p * (float)vv[t][2];
    o3 += p * (float)vv[t][3];
  }
  o0 += __shfl_xor(o0, 16); o0 += __shfl_xor(o0, 32);
  o1 += __shfl_xor(o1, 16); o1 += __shfl_xor(o1, 32);
  o2 += __shfl_xor(o2, 16); o2 += __shfl_xor(o2, 32);
  o3 += __shfl_xor(o3, 16); o3 += __shfl_xor(o3, 32);

  if (g == 0) {
    half4 hv;
    hv[0] = (_Float16)o0; hv[1] = (_Float16)o1;
    hv[2] = (_Float16)o2; hv[3] = (_Float16)o3;
    *(half4*)(ao + (row_base + q) * DIM + hoff + 4 * c) = hv;
  }
}

extern "C" void kernel_launch(void* const* d_in, const int* in_sizes, int n_in,
                              void* d_out, int out_size, void* d_ws, size_t ws_size,
                              hipStream_t stream) {
  const float* x      = (const float*)d_in[0];
  const int*   routes = (const int*)  d_in[1];
  const float* qkv_w  = (const float*)d_in[2];
  const float* qkv_b  = (const float*)d_in[3];
  const float* out_w  = (const float*)d_in[4];
  const float* out_b  = (const float*)d_in[5];
  float* out = (float*)d_out;

  _Float16* qkvh = (_Float16*)d_ws;                       // 4096*3072
  _Float16* aoh  = qkvh + (size_t)MROWS * QKV_DIM;        // 4096*1024
  _Float16* xh   = aoh  + (size_t)MROWS * DIM;            // 4096*1024
  _Float16* wh   = xh   + (size_t)MROWS * DIM;            // 3072*1024
  _Float16* owh  = wh   + (size_t)QKV_DIM * DIM;          // 1024*1024

  cast3<<<1024, 256, 0, stream>>>(x, MROWS * DIM / 4,
                                  qkv_w, QKV_DIM * DIM / 4,
                                  out_w, DIM * DIM / 4,
                                  xh, wh, owh);

  // QKV projection: 128x128 tile, 768 blocks, plain 2D grid (r8 config)
  {
    dim3 g(QKV_DIM / 128, MROWS / 128);
    gemm_bt_f16<128, 128, true><<<g, 256, 0, stream>>>(xh, wh, qkv_b, qkvh,
                                                       MROWS, QKV_DIM, DIM);
  }

  attn_kernel<<<(BATCH * HEADS * SEQ) / 4, 256, 0, stream>>>(qkvh, routes, aoh);

  // output projection: 64x128 tile, 512 blocks (r8 config)
  {
    dim3 g(DIM / 128, MROWS / 64);
    gemm_bt_f16<64, 128, false><<<g, 256, 0, stream>>>(aoh, owh, out_b, out,
                                                       MROWS, DIM, DIM);
  }
}

// Round 13
// 207.510 us; speedup vs baseline: 1.1115x; 1.0351x over previous
//
#include <hip/hip_runtime.h>
#include <math.h>

#define BATCH    2
#define SEQ      2048
#define DIM      1024
#define HEADS    16
#define HEAD_DIM 64
#define K_NEI    64
#define QKV_DIM  3072
#define MROWS    (BATCH * SEQ)   // 4096
#define ATT_SCALE 0.125f

typedef _Float16 half8  __attribute__((ext_vector_type(8)));
typedef _Float16 half4  __attribute__((ext_vector_type(4)));
typedef _Float16 half2t __attribute__((ext_vector_type(2)));
typedef float    floatx4 __attribute__((ext_vector_type(4)));

__device__ inline void async_copy16(const void* g, void* l) {
  __builtin_amdgcn_global_load_lds(
      (const __attribute__((address_space(1))) unsigned int*)g,
      (__attribute__((address_space(3))) unsigned int*)l, 16, 0, 0);
}

__device__ inline float dot2h(half2t a, half2t b, float c) {
#if defined(__has_builtin) && __has_builtin(__builtin_amdgcn_fdot2)
  return __builtin_amdgcn_fdot2(a, b, c, false);
#else
  return c + (float)a[0] * (float)b[0] + (float)a[1] * (float)b[1];
#endif
}

// fused fp32 -> f16 cast of three tensors (sizes in float4 groups)
__global__ __launch_bounds__(256)
void cast3(const float* __restrict__ a, int na4,
           const float* __restrict__ b, int nb4,
           const float* __restrict__ c, int nc4,
           _Float16* __restrict__ oa, _Float16* __restrict__ ob,
           _Float16* __restrict__ oc) {
  const int total = na4 + nb4 + nc4;
  for (int i = blockIdx.x * blockDim.x + threadIdx.x; i < total;
       i += gridDim.x * blockDim.x) {
    const float* src; _Float16* dst; int idx;
    if (i < na4)            { src = a; dst = oa; idx = i; }
    else if (i < na4 + nb4) { src = b; dst = ob; idx = i - na4; }
    else                    { src = c; dst = oc; idx = i - na4 - nb4; }
    float4 v = *(const float4*)(src + (size_t)idx * 4);
    half4 o;
    o[0] = (_Float16)v.x; o[1] = (_Float16)v.y;
    o[2] = (_Float16)v.z; o[3] = (_Float16)v.w;
    *(half4*)(dst + (size_t)idx * 4) = o;
  }
}

// C[m,n] = sum_k A[m,k]*B[n,k] + bias[n]; A:[M,K] f16, B:[N,K] f16.
// BK=64 as two 32-wide sub-tiles staged together -> one barrier pair / 64 K.
// Best-measured config (round-7 submission, 209.9 us total).
template<int BM, int BN, bool HALF_OUT>
__global__ __launch_bounds__(256)
void gemm_bt_f16(const _Float16* __restrict__ A, const _Float16* __restrict__ B,
                 const float* __restrict__ bias, void* __restrict__ Cv,
                 int M, int N, int K) {
  constexpr int FI = BM / 32;
  constexpr int FJ = BN / 32;
  constexpr int CA = BM / 64;
  constexpr int CB = BN / 64;
  __shared__ _Float16 As[2 * BM * 32];
  __shared__ _Float16 Bs[2 * BN * 32];

  const int tid  = threadIdx.x;
  const int lane = tid & 63;
  const int w    = tid >> 6;
  const int wr   = w >> 1;
  const int wc   = w & 1;
  const int bm   = blockIdx.y * BM;
  const int bn   = blockIdx.x * BN;

  const int srow = w * 16 + (lane >> 2);
  const int scol = (lane & 3) * 8;
  const _Float16* ga = A + (size_t)(bm + srow) * K + scol;
  const _Float16* gb = B + (size_t)(bn + srow) * K + scol;

  const int frow = lane & 15;
  const int fk   = (lane >> 4) * 8;

  floatx4 acc[FI][FJ] = {};

  for (int k0 = 0; k0 < K; k0 += 64) {
#pragma unroll
    for (int sub = 0; sub < 2; sub++) {
      const int kk = k0 + sub * 32;
#pragma unroll
      for (int i = 0; i < CA; i++)
        async_copy16(ga + (size_t)(i * 64) * K + kk,
                     As + sub * BM * 32 + w * 512 + i * 2048);
#pragma unroll
      for (int i = 0; i < CB; i++)
        async_copy16(gb + (size_t)(i * 64) * K + kk,
                     Bs + sub * BN * 32 + w * 512 + i * 2048);
    }
    __syncthreads();

#pragma unroll
    for (int sub = 0; sub < 2; sub++) {
      half8 af[FI], bf[FJ];
#pragma unroll
      for (int i = 0; i < FI; i++)
        af[i] = *(const half8*)&As[sub * BM * 32 + (wr * (BM / 2) + i * 16 + frow) * 32 + fk];
#pragma unroll
      for (int j = 0; j < FJ; j++)
        bf[j] = *(const half8*)&Bs[sub * BN * 32 + (wc * (BN / 2) + j * 16 + frow) * 32 + fk];
#pragma unroll
      for (int i = 0; i < FI; i++)
#pragma unroll
        for (int j = 0; j < FJ; j++) {
          if (HALF_OUT)
            acc[i][j] = __builtin_amdgcn_mfma_f32_16x16x32_f16(bf[j], af[i], acc[i][j], 0, 0, 0);
          else
            acc[i][j] = __builtin_amdgcn_mfma_f32_16x16x32_f16(af[i], bf[j], acc[i][j], 0, 0, 0);
        }
    }
    __syncthreads();
  }

  if (HALF_OUT) {
    _Float16* C = (_Float16*)Cv;
    const int mloc = lane & 15;
    const int nloc = (lane >> 4) * 4;
#pragma unroll
    for (int j = 0; j < FJ; j++) {
      const int gcol = bn + wc * (BN / 2) + j * 16 + nloc;
      float4 bj = *(const float4*)(bias + gcol);
#pragma unroll
      for (int i = 0; i < FI; i++) {
        const int grow = bm + wr * (BM / 2) + i * 16 + mloc;
        half4 hv;
        hv[0] = (_Float16)(acc[i][j][0] + bj.x);
        hv[1] = (_Float16)(acc[i][j][1] + bj.y);
        hv[2] = (_Float16)(acc[i][j][2] + bj.z);
        hv[3] = (_Float16)(acc[i][j][3] + bj.w);
        *(half4*)(C + (size_t)grow * N + gcol) = hv;
      }
    }
  } else {
    float* C = (float*)Cv;
    const int crow = (lane >> 4) * 4;
    const int ccol = lane & 15;
#pragma unroll
    for (int j = 0; j < FJ; j++) {
      const int gcol = bn + wc * (BN / 2) + j * 16 + ccol;
      const float bj = bias[gcol];
#pragma unroll
      for (int i = 0; i < FI; i++) {
        const int grow = bm + wr * (BM / 2) + i * 16 + crow;
        float* cp = C + (size_t)grow * N + gcol;
#pragma unroll
        for (int r = 0; r < 4; r++)
          cp[(size_t)r * N] = acc[i][j][r] + bj;
      }
    }
  }
}

// Quad-cooperative gathered attention, LDS-transpose reduction (best-measured
// 80.8 us; four decompositions plateau at ~80 us — limiter is L2/L3 delivery
// of the irreducible 1.07 GB gather at ~13 TB/s effective).
__global__ __launch_bounds__(256)
void attn_kernel(const _Float16* __restrict__ qkv,
                 const int* __restrict__ routes,
                 _Float16* __restrict__ ao) {
  const int lane = threadIdx.x & 63;
  const int w    = threadIdx.x >> 6;
  const int g    = lane >> 4;
  const int c    = lane & 15;

  const int i    = blockIdx.x;
  const int xcd  = i & 7;
  const int j    = i >> 3;
  const int bh   = j >> 6;
  const int qsub = j & 63;
  const int qblk = xcd * 64 + qsub;
  const int q    = qblk * 4 + w;
  const int h    = bh & 15;
  const int b    = bh >> 4;

  __shared__ float scratch[4][16 * 68];
  float* sw = scratch[w];

  const size_t row_base = (size_t)b * SEQ;
  const int    hoff     = h * HEAD_DIM;

  const int* rbase = routes + q * K_NEI + g;
  int rq[16];
#pragma unroll
  for (int t = 0; t < 16; t++) rq[t] = rbase[4 * t];

  const half4 qv = *(const half4*)(qkv + (row_base + q) * QKV_DIM + hoff + 4 * c);
  const half2t qv01 = { qv[0], qv[1] };
  const half2t qv23 = { qv[2], qv[3] };

  half4 vv[16];

#pragma unroll
  for (int t = 0; t < 16; t++) {
    const _Float16* kp = qkv + (row_base + rq[t]) * QKV_DIM + DIM + hoff + 4 * c;
    half4 kv = *(const half4*)kp;
    vv[t]    = *(const half4*)(kp + DIM);
    half2t k01 = { kv[0], kv[1] };
    half2t k23 = { kv[2], kv[3] };
    float sp = dot2h(k23, qv23, dot2h(k01, qv01, 0.f));
    sw[t * 68 + lane] = sp;
  }

  const int rb = (lane >> 2) * 68 + (lane & 3) * 16;
  float4 p0 = *(const float4*)&sw[rb];
  float4 p1 = *(const float4*)&sw[rb + 4];
  float4 p2 = *(const float4*)&sw[rb + 8];
  float4 p3 = *(const float4*)&sw[rb + 12];
  float sc = ((p0.x + p0.y) + (p0.z + p0.w)) + ((p1.x + p1.y) + (p1.z + p1.w))
           + ((p2.x + p2.y) + (p2.z + p2.w)) + ((p3.x + p3.y) + (p3.z + p3.w));

  float m = sc;
#pragma unroll
  for (int off = 1; off < 64; off <<= 1) m = fmaxf(m, __shfl_xor(m, off));
  float e = __expf((sc - m) * ATT_SCALE);
  float sum = e;
#pragma unroll
  for (int off = 1; off < 64; off <<= 1) sum += __shfl_xor(sum, off);
  const float pn = e / sum;

  sw[lane] = pn;
  float o0 = 0.f, o1 = 0.f, o2 = 0.f, o3 = 0.f;
#pragma unroll
  for (int t = 0; t < 16; t++) {
    const float p = sw[4 * t + g];
    o0 += p * (float)vv[t][0];
    o1 += p * (float)vv[t][1];
    o2 += p * (float)vv[t][2];
    o3 += p * (float)vv[t][3];
  }
  o0 += __shfl_xor(o0, 16); o0 += __shfl_xor(o0, 32);
  o1 += __shfl_xor(o1, 16); o1 += __shfl_xor(o1, 32);
  o2 += __shfl_xor(o2, 16); o2 += __shfl_xor(o2, 32);
  o3 += __shfl_xor(o3, 16); o3 += __shfl_xor(o3, 32);

  if (g == 0) {
    half4 hv;
    hv[0] = (_Float16)o0; hv[1] = (_Float16)o1;
    hv[2] = (_Float16)o2; hv[3] = (_Float16)o3;
    *(half4*)(ao + (row_base + q) * DIM + hoff + 4 * c) = hv;
  }
}

extern "C" void kernel_launch(void* const* d_in, const int* in_sizes, int n_in,
                              void* d_out, int out_size, void* d_ws, size_t ws_size,
                              hipStream_t stream) {
  const float* x      = (const float*)d_in[0];
  const int*   routes = (const int*)  d_in[1];
  const float* qkv_w  = (const float*)d_in[2];
  const float* qkv_b  = (const float*)d_in[3];
  const float* out_w  = (const float*)d_in[4];
  const float* out_b  = (const float*)d_in[5];
  float* out = (float*)d_out;

  _Float16* qkvh = (_Float16*)d_ws;                       // 4096*3072
  _Float16* aoh  = qkvh + (size_t)MROWS * QKV_DIM;        // 4096*1024
  _Float16* xh   = aoh  + (size_t)MROWS * DIM;            // 4096*1024
  _Float16* wh   = xh   + (size_t)MROWS * DIM;            // 3072*1024
  _Float16* owh  = wh   + (size_t)QKV_DIM * DIM;          // 1024*1024

  cast3<<<1024, 256, 0, stream>>>(x, MROWS * DIM / 4,
                                  qkv_w, QKV_DIM * DIM / 4,
                                  out_w, DIM * DIM / 4,
                                  xh, wh, owh);

  // QKV projection: 128x128 tile, 768 blocks
  {
    dim3 g(QKV_DIM / 128, MROWS / 128);
    gemm_bt_f16<128, 128, true><<<g, 256, 0, stream>>>(xh, wh, qkv_b, qkvh,
                                                       MROWS, QKV_DIM, DIM);
  }

  attn_kernel<<<(BATCH * HEADS * SEQ) / 4, 256, 0, stream>>>(qkvh, routes, aoh);

  // output projection: 64x128 tile, 512 blocks
  {
    dim3 g(DIM / 128, MROWS / 64);
    gemm_bt_f16<64, 128, false><<<g, 256, 0, stream>>>(aoh, owh, out_b, out,
                                                       MROWS, DIM, DIM);
  }
}